// Round 15
// baseline (161.248 us; speedup 1.0000x reference)
//
#include <hip/hip_runtime.h>
#include <math.h>

// Problem constants
#define N_TOK 32768      // 32*32*32 tokens
#define NE    1024       // codebook size
#define DIM   256        // code dim
#define EPS   8.0e-4f    // candidate margin: prepass dist-err sigma ~7e-5 -> ~11 sigma

// d_out layout (fp32 elements):
//  [0] loss | [1..8388609) z_q_st | [8388609] ppl | [8388610..+33554432) one_hot
//  | [41943042..+32768) indices (float)
#define OFF_ZQ   1u
#define OFF_PPL  8388609u
#define OFF_OH   8388610u
#define OFF_IDX  41943042u

#define RS_CAP 4096
#define RS_TOK 16

typedef __attribute__((ext_vector_type(8))) short short8;
typedef __attribute__((ext_vector_type(8))) unsigned short ushort8;
typedef __attribute__((ext_vector_type(4))) float f32x4;
typedef __attribute__((ext_vector_type(2))) float f32x2;

__device__ __forceinline__ unsigned short bf_rne(float f) {
    unsigned u = __float_as_uint(f);
    return (unsigned short)((u + 0x7FFFu + ((u >> 16) & 1u)) >> 16);
}
__device__ __forceinline__ void gload16(const void* g, void* l) {
    __builtin_amdgcn_global_load_lds((const __attribute__((address_space(1))) void*)g,
                                     (__attribute__((address_space(3))) void*)l, 16, 0, 0);
}

// ---------------------------------------------------------------------------
// e-side prep only (z-side now fused into argmin): RNE bf16 e1 + exact en
// (ascending-fmaf, bit-identical to all prior rounds) + SSE zero + hist zero.
// ---------------------------------------------------------------------------
__global__ __launch_bounds__(256) void vq_eprep(const float* __restrict__ ew,
                                                unsigned short* __restrict__ e1,
                                                float* __restrict__ en,
                                                float* __restrict__ sse,
                                                int* __restrict__ hist)
{
    const int t = threadIdx.x;
    if (blockIdx.x == 0 && t == 0) sse[0] = 0.0f;
    const int code = (int)blockIdx.x * 256 + t;
    if (hist) hist[code] = 0;
    const float* p = ew + (size_t)code * DIM;
    float s = 0.0f;
    for (int dg = 0; dg < 32; ++dg) {
        ushort8 s1;
#pragma unroll
        for (int j = 0; j < 8; ++j) {
            float v = p[dg * 8 + j];
            s = fmaf(v, v, s);
            s1[j] = bf_rne(v);
        }
        *reinterpret_cast<ushort8*>(e1 + (size_t)code * 256 + dg * 8) = s1;
    }
    en[code] = s;
}

// ---------------------------------------------------------------------------
// Fused MFMA prepass: 128 tokens x 128 codes per block, 4 waves (2x2), BK=32,
// 1 product (trunc-bf16(z) * e1). za is staged DIRECTLY from fp32 z (waves
// 0-1: wave-coalesced 256B/channel reads, trunc to bf16, ds_write_b128 into
// the same swizzled layout as before); eb keeps the proven gload16 path
// (waves 2-3, old code verbatim). The z-wave also accumulates zn in the exact
// ascending-fmaf order (chunk 0..7, j 0..31) -> zn bit-identical to prep's.
// z1 intermediate is eliminated (-50 MB traffic, -1 kernel).
// Output: per-token 128-bit candidate mask (d <= blockmin + EPS) per block.
// ---------------------------------------------------------------------------
__global__ __launch_bounds__(256) void vq_argmin_mfma(const float* __restrict__ z,
                                                      const unsigned short* __restrict__ e1,
                                                      const float* __restrict__ en,
                                                      unsigned long long* __restrict__ cmu,
                                                      float* __restrict__ zn)
{
    __shared__ short lds[2][8192];   // per buf: za [0..4095], eb [4096..8191]

    const int t = threadIdx.x;
    const int lane = t & 63, w = t >> 6;
    const int wr = w >> 1, wc = w & 1;
    const int bid = (blockIdx.x & 7) * 256 + (blockIdx.x >> 3);   // XCD swizzle (2048 % 8 == 0)
    const int rb = bid >> 3, cbi = bid & 7;
    const int r0 = rb * 128, c0 = cbi * 128;
    const int img = r0 >> 10, hw0 = r0 & 1023;

    const bool zwave = (t < 128);

    // eb srcp (waves 2-3): identical math to prior rounds (arr==1 half)
    const char* srcp[4];
    if (!zwave) {
#pragma unroll
        for (int i = 0; i < 4; ++i) {
            int flat = (w * 4 + i) * 64 + lane;    // 512..1023 for w in {2,3}
            int rr  = (flat & 511) >> 2;            // code row 0..127
            int sl  = flat & 3;                     // physical k-slot
            int slx = sl ^ ((rr >> 1) & 3);         // source k-slot (pre-swizzle)
            srcp[i] = (const char*)(e1 + (size_t)(c0 + rr) * 256 + slx * 8);
        }
    }

    const float* zbase = z + (size_t)img * (DIM * 1024) + hw0 + t;  // t = token row (zwave)
    const int swz = (t >> 1) & 3;
    float znacc = 0.0f;

    f32x4 acc[4][4];
#pragma unroll
    for (int i = 0; i < 4; ++i)
#pragma unroll
        for (int j = 0; j < 4; ++j) acc[i][j] = (f32x4)0.0f;

    // ---- prologue: stage chunk 0 into buf 0
    if (zwave) {
        ushort8 pk[4];
#pragma unroll
        for (int s = 0; s < 4; ++s) {
#pragma unroll
            for (int j = 0; j < 8; ++j) {
                float v = zbase[(size_t)(s * 8 + j) * 1024];
                znacc = fmaf(v, v, znacc);
                pk[s][j] = (unsigned short)(__float_as_uint(v) >> 16);
            }
        }
        short* dst = &lds[0][t * 32];
#pragma unroll
        for (int s = 0; s < 4; ++s)
            *reinterpret_cast<ushort8*>(dst + ((s ^ swz) * 8)) = pk[s];
    } else {
#pragma unroll
        for (int i = 0; i < 4; ++i)
            gload16(srcp[i], &lds[0][(w * 4 + i) * 512]);
    }
    __syncthreads();

    int cur = 0;
    for (int kc = 0; kc < 8; ++kc) {
        if (kc < 7) {
            const int kcn = kc + 1;
            if (zwave) {
                const float* zc = zbase + (size_t)(kcn * 32) * 1024;
                ushort8 pk[4];
#pragma unroll
                for (int s = 0; s < 4; ++s) {
#pragma unroll
                    for (int j = 0; j < 8; ++j) {
                        float v = zc[(size_t)(s * 8 + j) * 1024];
                        znacc = fmaf(v, v, znacc);
                        pk[s][j] = (unsigned short)(__float_as_uint(v) >> 16);
                    }
                }
                short* dst = &lds[cur ^ 1][t * 32];
#pragma unroll
                for (int s = 0; s < 4; ++s)
                    *reinterpret_cast<ushort8*>(dst + ((s ^ swz) * 8)) = pk[s];
            } else {
                const unsigned kadd = (unsigned)kcn * 64u;   // +32 bf16 per chunk
#pragma unroll
                for (int i = 0; i < 4; ++i)
                    gload16(srcp[i] + kadd, &lds[cur ^ 1][(w * 4 + i) * 512]);
            }
        }
        const short* L = &lds[cur][0];
        const short* za = L;
        const short* eb = L + 4096;

        short8 bfr[4];
#pragma unroll
        for (int fn = 0; fn < 4; ++fn) {
            int row = wc * 64 + fn * 16 + (lane & 15);
            int slot = (lane >> 4) ^ ((row >> 1) & 3);
            bfr[fn] = *reinterpret_cast<const short8*>(eb + row * 32 + slot * 8);
        }
#pragma unroll
        for (int fm = 0; fm < 4; ++fm) {
            int row = wr * 64 + fm * 16 + (lane & 15);
            int slot = (lane >> 4) ^ ((row >> 1) & 3);
            short8 a0 = *reinterpret_cast<const short8*>(za + row * 32 + slot * 8);
#pragma unroll
            for (int fn = 0; fn < 4; ++fn)
                acc[fm][fn] = __builtin_amdgcn_mfma_f32_16x16x32_bf16(a0, bfr[fn], acc[fm][fn], 0, 0, 0);
        }
        __syncthreads();
        cur ^= 1;
    }

    // zn: exact ascending-fmaf over c=0..255 (bit-identical to old prep);
    // only the cbi==0 sibling writes (all siblings compute identical bits).
    if (zwave && cbi == 0) zn[r0 + t] = znacc;

    // ---- epilogue phase 1: per-row block-min (cross-wave merged, race-free)
    float env[4];
#pragma unroll
    for (int fn = 0; fn < 4; ++fn)
        env[fn] = en[c0 + wc * 64 + fn * 16 + (lane & 15)];

    float* sdm = reinterpret_cast<float*>(&lds[0][0]);   // [2][128]

#pragma unroll
    for (int fm = 0; fm < 4; ++fm) {
#pragma unroll
        for (int reg = 0; reg < 4; ++reg) {
            int lrow = wr * 64 + fm * 16 + ((lane >> 4) << 2) + reg;
            float bd = 3.0e38f;
#pragma unroll
            for (int fn = 0; fn < 4; ++fn) {
                float dv = env[fn] - 2.0f * acc[fm][fn][reg];
                bd = fminf(bd, dv);
            }
#pragma unroll
            for (int m = 1; m <= 8; m <<= 1)
                bd = fminf(bd, __shfl_xor(bd, m));
            if ((lane & 15) == 0) sdm[wc * 128 + lrow] = bd;
        }
    }
    __syncthreads();
    if (t < 128) sdm[t] = fminf(sdm[t], sdm[128 + t]) + EPS;   // threshold per row
    __syncthreads();

    // ---- epilogue phase 2: ballot candidates, assemble 64-bit half-masks
#pragma unroll
    for (int fm = 0; fm < 4; ++fm) {
        unsigned long long bl[4][4];
#pragma unroll
        for (int fn = 0; fn < 4; ++fn) {
#pragma unroll
            for (int reg = 0; reg < 4; ++reg) {
                int lrow = wr * 64 + fm * 16 + ((lane >> 4) << 2) + reg;
                float thr = sdm[lrow];
                float dv = env[fn] - 2.0f * acc[fm][fn][reg];
                bl[fn][reg] = __ballot(dv <= thr);
            }
        }
        const int q = lane >> 4;
#pragma unroll
        for (int reg = 0; reg < 4; ++reg) {
            unsigned long long h =
                  ((bl[0][reg] >> (q * 16)) & 0xFFFFull)
                | (((bl[1][reg] >> (q * 16)) & 0xFFFFull) << 16)
                | (((bl[2][reg] >> (q * 16)) & 0xFFFFull) << 32)
                | (((bl[3][reg] >> (q * 16)) & 0xFFFFull) << 48);
            if ((lane & 15) == reg) {
                int row = wr * 64 + fm * 16 + q * 4 + reg;
                cmu[(size_t)(r0 + row) * 16 + cbi * 2 + wc] = h;
            }
        }
    }
}

// ---------------------------------------------------------------------------
// Exact rescore + fused z_q gather + SSE + one_hot full rows + histogram.
// One block = 16 tokens. XCD-bijective swizzle keeps 128B-z-line-sharing
// block pairs on one XCD (L2 absorbs the half-line overlap on reads+writes).
// z_q stores regular (L2-merged); one_hot rows nontemporal.
// Rescore formula identical to rounds 5-14 (bitwise-stable indices).
// ---------------------------------------------------------------------------
__global__ __launch_bounds__(256) void vq_rescore(const float* __restrict__ z,
                                                  const float* __restrict__ ew,
                                                  const float* __restrict__ zn,
                                                  const float* __restrict__ en,
                                                  const unsigned long long* __restrict__ cmu,
                                                  float* __restrict__ out_idx,
                                                  float* __restrict__ zq,
                                                  float* __restrict__ sse,
                                                  float* __restrict__ oh,
                                                  int* __restrict__ hist)
{
    __shared__ float zrow[RS_TOK * 260];            // 16.6 KB, float4-aligned rows
    __shared__ unsigned short wl[RS_CAP];           // 8 KB worklist: (tok<<10)|code
    __shared__ int   wsum[4];
    __shared__ float redf[256];
    __shared__ unsigned long long best[RS_TOK];

    const int t = threadIdx.x, lane = t & 63, w = t >> 6;
    const int bid = (blockIdx.x & 7) * 256 + (blockIdx.x >> 3);   // XCD swizzle (2048 % 8 == 0)
    const int tok0 = bid * RS_TOK;
    const int img = tok0 >> 10, hw0 = tok0 & 1023;

    // stage 16 z-rows from original z: lane owns channel c=t, 4 float4 along hw
    {
        const float* zc = z + (size_t)img * (DIM * 1024) + (size_t)t * 1024 + hw0;
#pragma unroll
        for (int j = 0; j < 4; ++j) {
            float4 v = *reinterpret_cast<const float4*>(zc + 4 * j);
            zrow[(4 * j + 0) * 260 + t] = v.x;
            zrow[(4 * j + 1) * 260 + t] = v.y;
            zrow[(4 * j + 2) * 260 + t] = v.z;
            zrow[(4 * j + 3) * 260 + t] = v.w;
        }
    }
    if (t < RS_TOK) best[t] = ~0ull;

    // one mask word per thread: tok = t>>4, wd = t&15; wave-shfl scan
    unsigned long long v = cmu[(size_t)(tok0 + (t >> 4)) * 16 + (t & 15)];
    int myc = __popcll(v);
    int x = myc;
#pragma unroll
    for (int d = 1; d < 64; d <<= 1) {
        int y = __shfl_up(x, d);
        if (lane >= d) x += y;
    }
    if (lane == 63) wsum[w] = x;
    __syncthreads();
    int woff = 0;
#pragma unroll
    for (int i = 0; i < 4; ++i) woff += (i < w) ? wsum[i] : 0;
    int total = wsum[0] + wsum[1] + wsum[2] + wsum[3];
    int base = woff + x - myc;                      // global exclusive prefix
    {
        const int wd = t & 15, tk = t >> 4;
        unsigned long long vv = v;
        while (vv) {
            int b = __ffsll((long long)vv) - 1;
            vv &= vv - 1;
            int code = (wd >> 1) * 128 + (wd & 1) * 64 + b;
            if (base < RS_CAP) wl[base] = (unsigned short)((tk << 10) | code);
            ++base;
        }
    }
    __syncthreads();
    if (total > RS_CAP) total = RS_CAP;

    for (int p = t; p < total; p += 256) {
        int e = (int)wl[p];
        int tk = e >> 10, code = e & 1023;
        const float* ep = ew + (size_t)code * DIM;
        const float* zr = &zrow[tk * 260];
        float s = 0.0f;
#pragma unroll 8
        for (int d = 0; d < DIM; d += 4) {
            float4 e4 = *reinterpret_cast<const float4*>(ep + d);
            float4 z4 = *reinterpret_cast<const float4*>(zr + d);
            s = fmaf(z4.x, e4.x, s);
            s = fmaf(z4.y, e4.y, s);
            s = fmaf(z4.z, e4.z, s);
            s = fmaf(z4.w, e4.w, s);
        }
        float dv = (zn[tok0 + tk] + en[code]) - 2.0f * s;
        unsigned long long key = ((unsigned long long)__float_as_uint(dv) << 32) | (unsigned)code;
        atomicMin(&best[tk], key);
    }
    __syncthreads();
    if (t < RS_TOK) {
        int bi = (int)(best[t] & 0x3FFu);
        out_idx[tok0 + t] = (float)bi;
        if (hist) atomicAdd(&hist[bi], 1);
    }

    // ---- fused z_q gather + SSE (z rows already in LDS); regular stores so
    // L2 merges the 64B half-lines from the paired block on this XCD
    const int tk2 = t & 15, cg2 = t >> 4;
    const int bidx = (int)(best[tk2] & 0x3FFu);
    const int hwp = hw0 + tk2;
    float part = 0.0f;
    float* zqb = zq + (size_t)img * (DIM * 1024) + hwp;
    const float* ewb = ew + (size_t)bidx * DIM;
#pragma unroll
    for (int i = 0; i < 16; ++i) {
        int c = cg2 * 16 + i;
        float q = ewb[c];
        float zv = zrow[tk2 * 260 + c];
        zqb[(size_t)c << 10] = q;                  // 64B segments, L2-merged
        float dx = q - zv;
        part = fmaf(dx, dx, part);
    }
    redf[t] = part;
    __syncthreads();
    for (int s2 = 128; s2 > 0; s2 >>= 1) {
        if (t < s2) redf[t] += redf[t + s2];
        __syncthreads();
    }
    if (t == 0) atomicAdd(sse, redf[0]);

    // ---- fused one_hot full rows (nt stores, full-line streaming)
    if (oh) {
        const int w2 = t >> 6, lane2 = t & 63;
#pragma unroll
        for (int rr = 0; rr < 4; ++rr) {
            const int row = w2 * 4 + rr;           // 0..15
            const int bi2 = (int)(best[row] & 0x3FFull);
            float* rowp = oh + (size_t)(tok0 + row) * 1024;
#pragma unroll
            for (int j = 0; j < 4; ++j) {
                int i4 = j * 64 + lane2;
                if (i4 < 255) {                    // k = 2..1018 -> covers 2..1021
                    int k = 2 + i4 * 4;            // abs addr 16B-aligned (base = 8 mod 16)
                    f32x4 vv4;
                    vv4.x = (k     == bi2) ? 1.0f : 0.0f;
                    vv4.y = (k + 1 == bi2) ? 1.0f : 0.0f;
                    vv4.z = (k + 2 == bi2) ? 1.0f : 0.0f;
                    vv4.w = (k + 3 == bi2) ? 1.0f : 0.0f;
                    __builtin_nontemporal_store(vv4, reinterpret_cast<f32x4*>(rowp + k));
                }
            }
            if (lane2 == 0) {
                f32x2 v2; v2.x = (0 == bi2) ? 1.0f : 0.0f; v2.y = (1 == bi2) ? 1.0f : 0.0f;
                __builtin_nontemporal_store(v2, reinterpret_cast<f32x2*>(rowp));
            } else if (lane2 == 1) {
                f32x2 v2; v2.x = (1022 == bi2) ? 1.0f : 0.0f; v2.y = (1023 == bi2) ? 1.0f : 0.0f;
                __builtin_nontemporal_store(v2, reinterpret_cast<f32x2*>(rowp + 1022));
            }
        }
    }
}

// ---------------------------------------------------------------------------
// one_hot fallback kernel (scratch-in-oh path only): float2 stores
// ---------------------------------------------------------------------------
__global__ __launch_bounds__(256) void vq_onehot(const float* __restrict__ idxf,
                                                 float* __restrict__ oh)
{
    const unsigned stride = gridDim.x * blockDim.x;
    const unsigned total2 = N_TOK * (NE / 2);
    for (unsigned o2 = blockIdx.x * blockDim.x + threadIdx.x; o2 < total2; o2 += stride) {
        unsigned n = o2 >> 7;
        int k = (int)((o2 & 127u) << 1);
        int idx = (int)idxf[n];
        float2 v;
        v.x = (k == idx) ? 1.0f : 0.0f;
        v.y = (k + 1 == idx) ? 1.0f : 0.0f;
        reinterpret_cast<float2*>(oh)[o2] = v;
    }
}

// ---------------------------------------------------------------------------
// finalize: loss + perplexity. Big path: read the prebuilt histogram (1024
// loads). Fallback: rebuild from indices.
// ---------------------------------------------------------------------------
__global__ __launch_bounds__(1024) void vq_finalize(const int* __restrict__ histg,
                                                    const float* __restrict__ idxf,
                                                    const float* __restrict__ sse,
                                                    float* __restrict__ loss,
                                                    float* __restrict__ ppl)
{
    __shared__ int   hist[NE];
    __shared__ float red[NE];
    const int t = threadIdx.x;
    if (histg) {
        hist[t] = histg[t];
        __syncthreads();
    } else {
        hist[t] = 0;
        __syncthreads();
        const float2* idx2 = reinterpret_cast<const float2*>(idxf);
        for (int i = t; i < N_TOK / 2; i += 1024) {
            float2 v = idx2[i];
            atomicAdd(&hist[(int)v.x], 1);
            atomicAdd(&hist[(int)v.y], 1);
        }
        __syncthreads();
    }
    float p = (float)hist[t] * (1.0f / (float)N_TOK);
    red[t] = p * logf(p + 1e-10f);
    __syncthreads();
    for (int s = 512; s > 0; s >>= 1) {
        if (t < s) red[t] += red[t + s];
        __syncthreads();
    }
    if (t == 0) {
        ppl[0]  = expf(-red[0]);
        loss[0] = 0.25f * sse[0] / (float)(N_TOK * DIM);
    }
}

extern "C" void kernel_launch(void* const* d_in, const int* in_sizes, int n_in,
                              void* d_out, int out_size, void* d_ws, size_t ws_size,
                              hipStream_t stream)
{
    const float* z  = (const float*)d_in[0];   // (32,256,32,32)
    const float* ew = (const float*)d_in[1];   // (1024,256)
    float* out = (float*)d_out;

    float* out_idx = out + OFF_IDX;
    float* out_oh  = out + OFF_OH;
    float* out_zq  = out + OFF_ZQ;
    float* out_ppl = out + OFF_PPL;

    // Scratch placement: prefer d_ws (poison fills show ws ~672 MB). Fallback:
    // inside the one_hot output region (overwritten by vq_onehot afterwards).
    // Offsets keep 16B absolute alignment in both paths (oh base = 8 mod 16).
    const size_t need = 1024u + 524288u + 4194304u + 131072u + 16384u;
    const bool big = ws_size >= need && ws_size >= (size_t)48u * 1024u * 1024u;
    char* base = big ? (char*)d_ws : (char*)out_oh;
    const size_t E1o = big ? 1024u : 8u;
    const size_t CMo = E1o + 524288u;
    const size_t ZNo = CMo + 4194304u;
    const size_t ENo = ZNo + 131072u;
    const size_t HIo = ENo + 4096u;

    unsigned short* E1 = (unsigned short*)(base + E1o);
    unsigned long long* CM = (unsigned long long*)(base + CMo);
    float* ZN = (float*)(base + ZNo);
    float* EN = (float*)(base + ENo);
    int*   HI = big ? (int*)(base + HIo) : nullptr;
    float* SSE = (float*)d_ws;

    vq_eprep<<<4, 256, 0, stream>>>(ew, E1, EN, SSE, HI);
    vq_argmin_mfma<<<2048, 256, 0, stream>>>(z, E1, EN, CM, ZN);
    vq_rescore<<<2048, 256, 0, stream>>>(z, ew, ZN, EN, CM, out_idx, out_zq, SSE,
                                         big ? out_oh : nullptr, HI);
    if (!big) vq_onehot<<<2048, 256, 0, stream>>>(out_idx, out_oh);
    vq_finalize<<<1, 1024, 0, stream>>>(HI, out_idx, SSE, out, out_ppl);
}

// Round 16
// 129.243 us; speedup vs baseline: 1.2476x; 1.2476x over previous
//
#include <hip/hip_runtime.h>
#include <math.h>

// Problem constants
#define N_TOK 32768      // 32*32*32 tokens
#define NE    1024       // codebook size
#define DIM   256        // code dim
#define EPS   8.0e-4f    // candidate margin: prepass dist-err sigma ~7e-5 -> ~11 sigma

// d_out layout (fp32 elements):
//  [0] loss | [1..8388609) z_q_st | [8388609] ppl | [8388610..+33554432) one_hot
//  | [41943042..+32768) indices (float)
#define OFF_ZQ   1u
#define OFF_PPL  8388609u
#define OFF_OH   8388610u
#define OFF_IDX  41943042u

#define RS_CAP 4096
#define RS_TOK 16

typedef __attribute__((ext_vector_type(8))) short short8;
typedef __attribute__((ext_vector_type(8))) unsigned short ushort8;
typedef __attribute__((ext_vector_type(4))) float f32x4;
typedef __attribute__((ext_vector_type(2))) float f32x2;

__device__ __forceinline__ unsigned short bf_rne(float f) {
    unsigned u = __float_as_uint(f);
    return (unsigned short)((u + 0x7FFFu + ((u >> 16) & 1u)) >> 16);
}
__device__ __forceinline__ void gload16(const void* g, void* l) {
    __builtin_amdgcn_global_load_lds((const __attribute__((address_space(1))) void*)g,
                                     (__attribute__((address_space(3))) void*)l, 16, 0, 0);
}

// ---------------------------------------------------------------------------
// Fused prep: blocks 0..511 = z-side (transpose + trunc-bf16 z1 + exact zn),
// blocks 512..515 = e-side (RNE bf16 e1 + exact en) + SSE zero + hist zero.
// zn/en keep the SAME ascending-fmaf order as round 2 (bit-identical).
// ---------------------------------------------------------------------------
__global__ __launch_bounds__(256) void vq_prep(const float* __restrict__ z,
                                               const float* __restrict__ ew,
                                               unsigned short* __restrict__ z1,
                                               unsigned short* __restrict__ e1,
                                               float* __restrict__ zn,
                                               float* __restrict__ en,
                                               float* __restrict__ sse,
                                               int* __restrict__ hist)
{
    __shared__ float zf[64 * 257];   // [hw][c] padded stride 257
    const int t = threadIdx.x;

    if (blockIdx.x >= 512) {
        // ---- e-side (4 blocks x 256 threads = 1024 codes)
        if (blockIdx.x == 512 && t == 0) sse[0] = 0.0f;
        const int code = (int)(blockIdx.x - 512) * 256 + t;
        if (hist) hist[code] = 0;
        const float* p = ew + (size_t)code * DIM;
        float s = 0.0f;
        for (int dg = 0; dg < 32; ++dg) {
            ushort8 s1;
#pragma unroll
            for (int j = 0; j < 8; ++j) {
                float v = p[dg * 8 + j];
                s = fmaf(v, v, s);
                s1[j] = bf_rne(v);
            }
            *reinterpret_cast<ushort8*>(e1 + (size_t)code * 256 + dg * 8) = s1;
        }
        en[code] = s;
        return;
    }

    // ---- z-side: 512 blocks = 32 images x 16 hw-tiles of 64
    const int img = blockIdx.x >> 4;
    const int hw0 = (blockIdx.x & 15) << 6;
    const float* zb = z + (size_t)img * (DIM * 1024) + hw0;

    // stage tile 64 hw x 256 c with float4 reads (coalesced along hw)
#pragma unroll
    for (int it = 0; it < 16; ++it) {
        int f = it * 256 + t;                 // 4096 float4 slots
        int c = f >> 4, hw4 = f & 15;
        float4 v = *reinterpret_cast<const float4*>(zb + (size_t)c * 1024 + hw4 * 4);
        zf[(hw4 * 4 + 0) * 257 + c] = v.x;
        zf[(hw4 * 4 + 1) * 257 + c] = v.y;
        zf[(hw4 * 4 + 2) * 257 + c] = v.z;
        zf[(hw4 * 4 + 3) * 257 + c] = v.w;
    }
    __syncthreads();

    // zn: c-ascending fmaf (bit-identical to round 2)
    if (t < 64) {
        float s = 0.0f;
#pragma unroll 8
        for (int c = 0; c < DIM; ++c) { float v = zf[t * 257 + c]; s = fmaf(v, v, s); }
        zn[img * 1024 + hw0 + t] = s;
    }
    // no barrier needed: the split phase only READS zf

    // trunc-bf16 split, token-major, coalesced 16B stores (prepass-only data)
#pragma unroll
    for (int it = 0; it < 8; ++it) {
        int f = it * 256 + t;
        int tl = f >> 5, cg = f & 31;
        ushort8 s1;
#pragma unroll
        for (int j = 0; j < 8; ++j)
            s1[j] = (unsigned short)(__float_as_uint(zf[tl * 257 + cg * 8 + j]) >> 16);
        int tok = img * 1024 + hw0 + tl;
        *reinterpret_cast<ushort8*>(z1 + (size_t)tok * 256 + cg * 8) = s1;
    }
}

// ---------------------------------------------------------------------------
// MFMA prepass: 128 tokens x 128 codes per block, 4 waves (2x2), BK=32,
// 1 product (z1*e1). Per-row relative distance en - 2*dot. LDS 2 x 16KB.
// XCD-bijective swizzle keeps the 8 cbi-siblings of an rb on one XCD's L2.
// Output: per-token 128-bit candidate mask (d <= blockmin + EPS) per block.
// ---------------------------------------------------------------------------
__global__ __launch_bounds__(256) void vq_argmin_mfma(const unsigned short* __restrict__ z1,
                                                      const unsigned short* __restrict__ e1,
                                                      const float* __restrict__ en,
                                                      unsigned long long* __restrict__ cmu)
{
    __shared__ short lds[2][8192];   // per buf: za [0..4095], eb [4096..8191]

    const int t = threadIdx.x;
    const int lane = t & 63, w = t >> 6;
    const int wr = w >> 1, wc = w & 1;
    const int bid = (blockIdx.x & 7) * 256 + (blockIdx.x >> 3);   // XCD swizzle (2048 % 8 == 0)
    const int rb = bid >> 3, cbi = bid & 7;
    const int r0 = rb * 128, c0 = cbi * 128;

    const char* srcp[4];
#pragma unroll
    for (int i = 0; i < 4; ++i) {
        int flat = (w * 4 + i) * 64 + lane;    // 16B-slot id 0..1023
        int arr = flat >> 9;                    // 0 = z1, 1 = e1
        int rr  = (flat & 511) >> 2;            // row 0..127
        int sl  = flat & 3;                     // physical k-slot
        int slx = sl ^ ((rr >> 1) & 3);         // source k-slot (pre-swizzle)
        srcp[i] = (arr == 0)
            ? (const char*)(z1 + (size_t)(r0 + rr) * 256 + slx * 8)
            : (const char*)(e1 + (size_t)(c0 + rr) * 256 + slx * 8);
    }

    f32x4 acc[4][4];
#pragma unroll
    for (int i = 0; i < 4; ++i)
#pragma unroll
        for (int j = 0; j < 4; ++j) acc[i][j] = (f32x4)0.0f;

#pragma unroll
    for (int i = 0; i < 4; ++i)
        gload16(srcp[i], &lds[0][(w * 4 + i) * 512]);
    __syncthreads();

    int cur = 0;
    for (int kc = 0; kc < 8; ++kc) {
        if (kc < 7) {
            const unsigned kadd = (unsigned)(kc + 1) * 64u;   // +32 bf16 per chunk
#pragma unroll
            for (int i = 0; i < 4; ++i)
                gload16(srcp[i] + kadd, &lds[cur ^ 1][(w * 4 + i) * 512]);
        }
        const short* L = &lds[cur][0];
        const short* za = L;
        const short* eb = L + 4096;

        short8 bfr[4];
#pragma unroll
        for (int fn = 0; fn < 4; ++fn) {
            int row = wc * 64 + fn * 16 + (lane & 15);
            int slot = (lane >> 4) ^ ((row >> 1) & 3);
            bfr[fn] = *reinterpret_cast<const short8*>(eb + row * 32 + slot * 8);
        }
#pragma unroll
        for (int fm = 0; fm < 4; ++fm) {
            int row = wr * 64 + fm * 16 + (lane & 15);
            int slot = (lane >> 4) ^ ((row >> 1) & 3);
            short8 a0 = *reinterpret_cast<const short8*>(za + row * 32 + slot * 8);
#pragma unroll
            for (int fn = 0; fn < 4; ++fn)
                acc[fm][fn] = __builtin_amdgcn_mfma_f32_16x16x32_bf16(a0, bfr[fn], acc[fm][fn], 0, 0, 0);
        }
        __syncthreads();
        cur ^= 1;
    }

    // ---- epilogue phase 1: per-row block-min (cross-wave merged, race-free)
    float env[4];
#pragma unroll
    for (int fn = 0; fn < 4; ++fn)
        env[fn] = en[c0 + wc * 64 + fn * 16 + (lane & 15)];

    float* sdm = reinterpret_cast<float*>(&lds[0][0]);   // [2][128]

#pragma unroll
    for (int fm = 0; fm < 4; ++fm) {
#pragma unroll
        for (int reg = 0; reg < 4; ++reg) {
            int lrow = wr * 64 + fm * 16 + ((lane >> 4) << 2) + reg;
            float bd = 3.0e38f;
#pragma unroll
            for (int fn = 0; fn < 4; ++fn) {
                float dv = env[fn] - 2.0f * acc[fm][fn][reg];
                bd = fminf(bd, dv);
            }
#pragma unroll
            for (int m = 1; m <= 8; m <<= 1)
                bd = fminf(bd, __shfl_xor(bd, m));
            if ((lane & 15) == 0) sdm[wc * 128 + lrow] = bd;
        }
    }
    __syncthreads();
    if (t < 128) sdm[t] = fminf(sdm[t], sdm[128 + t]) + EPS;   // threshold per row
    __syncthreads();

    // ---- epilogue phase 2: ballot candidates, assemble 64-bit half-masks
#pragma unroll
    for (int fm = 0; fm < 4; ++fm) {
        unsigned long long bl[4][4];
#pragma unroll
        for (int fn = 0; fn < 4; ++fn) {
#pragma unroll
            for (int reg = 0; reg < 4; ++reg) {
                int lrow = wr * 64 + fm * 16 + ((lane >> 4) << 2) + reg;
                float thr = sdm[lrow];
                float dv = env[fn] - 2.0f * acc[fm][fn][reg];
                bl[fn][reg] = __ballot(dv <= thr);
            }
        }
        const int q = lane >> 4;
#pragma unroll
        for (int reg = 0; reg < 4; ++reg) {
            unsigned long long h =
                  ((bl[0][reg] >> (q * 16)) & 0xFFFFull)
                | (((bl[1][reg] >> (q * 16)) & 0xFFFFull) << 16)
                | (((bl[2][reg] >> (q * 16)) & 0xFFFFull) << 32)
                | (((bl[3][reg] >> (q * 16)) & 0xFFFFull) << 48);
            if ((lane & 15) == reg) {
                int row = wr * 64 + fm * 16 + q * 4 + reg;
                cmu[(size_t)(r0 + row) * 16 + cbi * 2 + wc] = h;
            }
        }
    }
}

// ---------------------------------------------------------------------------
// Exact rescore + fused z_q gather + SSE + one_hot full rows + histogram.
// One block = 16 tokens. XCD-bijective swizzle: each XCD owns 256 consecutive
// bids (= 4 images = 4MB of z, exactly one L2), so the two blocks sharing
// each 128B z line land on the SAME XCD -> L2 absorbs the half-line overlap
// on both the z reads and the z_q writes. z_q stores are regular (L2-merged);
// one_hot rows stay nontemporal (full-line streaming).
// Rescore formula identical to rounds 5-15 (bitwise-stable indices).
// ---------------------------------------------------------------------------
__global__ __launch_bounds__(256) void vq_rescore(const float* __restrict__ z,
                                                  const float* __restrict__ ew,
                                                  const float* __restrict__ zn,
                                                  const float* __restrict__ en,
                                                  const unsigned long long* __restrict__ cmu,
                                                  float* __restrict__ out_idx,
                                                  float* __restrict__ zq,
                                                  float* __restrict__ sse,
                                                  float* __restrict__ oh,
                                                  int* __restrict__ hist)
{
    __shared__ float zrow[RS_TOK * 260];            // 16.6 KB, float4-aligned rows
    __shared__ unsigned short wl[RS_CAP];           // 8 KB worklist: (tok<<10)|code
    __shared__ int   wsum[4];
    __shared__ float redf[256];
    __shared__ unsigned long long best[RS_TOK];

    const int t = threadIdx.x, lane = t & 63, w = t >> 6;
    const int bid = (blockIdx.x & 7) * 256 + (blockIdx.x >> 3);   // XCD swizzle (2048 % 8 == 0)
    const int tok0 = bid * RS_TOK;
    const int img = tok0 >> 10, hw0 = tok0 & 1023;

    // stage 16 z-rows from original z: lane owns channel c=t, 4 float4 along hw
    {
        const float* zc = z + (size_t)img * (DIM * 1024) + (size_t)t * 1024 + hw0;
#pragma unroll
        for (int j = 0; j < 4; ++j) {
            float4 v = *reinterpret_cast<const float4*>(zc + 4 * j);
            zrow[(4 * j + 0) * 260 + t] = v.x;
            zrow[(4 * j + 1) * 260 + t] = v.y;
            zrow[(4 * j + 2) * 260 + t] = v.z;
            zrow[(4 * j + 3) * 260 + t] = v.w;
        }
    }
    if (t < RS_TOK) best[t] = ~0ull;

    // one mask word per thread: tok = t>>4, wd = t&15; wave-shfl scan
    unsigned long long v = cmu[(size_t)(tok0 + (t >> 4)) * 16 + (t & 15)];
    int myc = __popcll(v);
    int x = myc;
#pragma unroll
    for (int d = 1; d < 64; d <<= 1) {
        int y = __shfl_up(x, d);
        if (lane >= d) x += y;
    }
    if (lane == 63) wsum[w] = x;
    __syncthreads();
    int woff = 0;
#pragma unroll
    for (int i = 0; i < 4; ++i) woff += (i < w) ? wsum[i] : 0;
    int total = wsum[0] + wsum[1] + wsum[2] + wsum[3];
    int base = woff + x - myc;                      // global exclusive prefix
    {
        const int wd = t & 15, tk = t >> 4;
        unsigned long long vv = v;
        while (vv) {
            int b = __ffsll((long long)vv) - 1;
            vv &= vv - 1;
            int code = (wd >> 1) * 128 + (wd & 1) * 64 + b;
            if (base < RS_CAP) wl[base] = (unsigned short)((tk << 10) | code);
            ++base;
        }
    }
    __syncthreads();
    if (total > RS_CAP) total = RS_CAP;

    for (int p = t; p < total; p += 256) {
        int e = (int)wl[p];
        int tk = e >> 10, code = e & 1023;
        const float* ep = ew + (size_t)code * DIM;
        const float* zr = &zrow[tk * 260];
        float s = 0.0f;
#pragma unroll 8
        for (int d = 0; d < DIM; d += 4) {
            float4 e4 = *reinterpret_cast<const float4*>(ep + d);
            float4 z4 = *reinterpret_cast<const float4*>(zr + d);
            s = fmaf(z4.x, e4.x, s);
            s = fmaf(z4.y, e4.y, s);
            s = fmaf(z4.z, e4.z, s);
            s = fmaf(z4.w, e4.w, s);
        }
        float dv = (zn[tok0 + tk] + en[code]) - 2.0f * s;
        unsigned long long key = ((unsigned long long)__float_as_uint(dv) << 32) | (unsigned)code;
        atomicMin(&best[tk], key);
    }
    __syncthreads();
    if (t < RS_TOK) {
        int bi = (int)(best[t] & 0x3FFu);
        out_idx[tok0 + t] = (float)bi;
        if (hist) atomicAdd(&hist[bi], 1);
    }

    // ---- fused z_q gather + SSE (z rows already in LDS); regular stores so
    // L2 merges the 64B half-lines from the paired block on this XCD
    const int tk2 = t & 15, cg2 = t >> 4;
    const int bidx = (int)(best[tk2] & 0x3FFu);
    const int hwp = hw0 + tk2;
    float part = 0.0f;
    float* zqb = zq + (size_t)img * (DIM * 1024) + hwp;
    const float* ewb = ew + (size_t)bidx * DIM;
#pragma unroll
    for (int i = 0; i < 16; ++i) {
        int c = cg2 * 16 + i;
        float q = ewb[c];
        float zv = zrow[tk2 * 260 + c];
        zqb[(size_t)c << 10] = q;                  // 64B segments, L2-merged
        float dx = q - zv;
        part = fmaf(dx, dx, part);
    }
    redf[t] = part;
    __syncthreads();
    for (int s2 = 128; s2 > 0; s2 >>= 1) {
        if (t < s2) redf[t] += redf[t + s2];
        __syncthreads();
    }
    if (t == 0) atomicAdd(sse, redf[0]);

    // ---- fused one_hot full rows (nt stores, full-line streaming)
    if (oh) {
        const int w2 = t >> 6, lane2 = t & 63;
#pragma unroll
        for (int rr = 0; rr < 4; ++rr) {
            const int row = w2 * 4 + rr;           // 0..15
            const int bi2 = (int)(best[row] & 0x3FFull);
            float* rowp = oh + (size_t)(tok0 + row) * 1024;
#pragma unroll
            for (int j = 0; j < 4; ++j) {
                int i4 = j * 64 + lane2;
                if (i4 < 255) {                    // k = 2..1018 -> covers 2..1021
                    int k = 2 + i4 * 4;            // abs addr 16B-aligned (base = 8 mod 16)
                    f32x4 vv4;
                    vv4.x = (k     == bi2) ? 1.0f : 0.0f;
                    vv4.y = (k + 1 == bi2) ? 1.0f : 0.0f;
                    vv4.z = (k + 2 == bi2) ? 1.0f : 0.0f;
                    vv4.w = (k + 3 == bi2) ? 1.0f : 0.0f;
                    __builtin_nontemporal_store(vv4, reinterpret_cast<f32x4*>(rowp + k));
                }
            }
            if (lane2 == 0) {
                f32x2 v2; v2.x = (0 == bi2) ? 1.0f : 0.0f; v2.y = (1 == bi2) ? 1.0f : 0.0f;
                __builtin_nontemporal_store(v2, reinterpret_cast<f32x2*>(rowp));
            } else if (lane2 == 1) {
                f32x2 v2; v2.x = (1022 == bi2) ? 1.0f : 0.0f; v2.y = (1023 == bi2) ? 1.0f : 0.0f;
                __builtin_nontemporal_store(v2, reinterpret_cast<f32x2*>(rowp + 1022));
            }
        }
    }
}

// ---------------------------------------------------------------------------
// one_hot fallback kernel (scratch-in-oh path only): float2 stores
// ---------------------------------------------------------------------------
__global__ __launch_bounds__(256) void vq_onehot(const float* __restrict__ idxf,
                                                 float* __restrict__ oh)
{
    const unsigned stride = gridDim.x * blockDim.x;
    const unsigned total2 = N_TOK * (NE / 2);
    for (unsigned o2 = blockIdx.x * blockDim.x + threadIdx.x; o2 < total2; o2 += stride) {
        unsigned n = o2 >> 7;
        int k = (int)((o2 & 127u) << 1);
        int idx = (int)idxf[n];
        float2 v;
        v.x = (k == idx) ? 1.0f : 0.0f;
        v.y = (k + 1 == idx) ? 1.0f : 0.0f;
        reinterpret_cast<float2*>(oh)[o2] = v;
    }
}

// ---------------------------------------------------------------------------
// finalize: loss + perplexity. Big path: read the prebuilt histogram (1024
// loads). Fallback: rebuild from indices.
// ---------------------------------------------------------------------------
__global__ __launch_bounds__(1024) void vq_finalize(const int* __restrict__ histg,
                                                    const float* __restrict__ idxf,
                                                    const float* __restrict__ sse,
                                                    float* __restrict__ loss,
                                                    float* __restrict__ ppl)
{
    __shared__ int   hist[NE];
    __shared__ float red[NE];
    const int t = threadIdx.x;
    if (histg) {
        hist[t] = histg[t];
        __syncthreads();
    } else {
        hist[t] = 0;
        __syncthreads();
        const float2* idx2 = reinterpret_cast<const float2*>(idxf);
        for (int i = t; i < N_TOK / 2; i += 1024) {
            float2 v = idx2[i];
            atomicAdd(&hist[(int)v.x], 1);
            atomicAdd(&hist[(int)v.y], 1);
        }
        __syncthreads();
    }
    float p = (float)hist[t] * (1.0f / (float)N_TOK);
    red[t] = p * logf(p + 1e-10f);
    __syncthreads();
    for (int s = 512; s > 0; s >>= 1) {
        if (t < s) red[t] += red[t + s];
        __syncthreads();
    }
    if (t == 0) {
        ppl[0]  = expf(-red[0]);
        loss[0] = 0.25f * sse[0] / (float)(N_TOK * DIM);
    }
}

extern "C" void kernel_launch(void* const* d_in, const int* in_sizes, int n_in,
                              void* d_out, int out_size, void* d_ws, size_t ws_size,
                              hipStream_t stream)
{
    const float* z  = (const float*)d_in[0];   // (32,256,32,32)
    const float* ew = (const float*)d_in[1];   // (1024,256)
    float* out = (float*)d_out;

    float* out_idx = out + OFF_IDX;
    float* out_oh  = out + OFF_OH;
    float* out_zq  = out + OFF_ZQ;
    float* out_ppl = out + OFF_PPL;

    // Scratch placement: prefer d_ws (poison fills show ws ~672 MB). Fallback:
    // inside the one_hot output region (overwritten by vq_onehot afterwards).
    // Offsets keep 16B absolute alignment in both paths (oh base = 8 mod 16).
    const size_t need = 1024u + 33554432u + 524288u + 4194304u + 131072u + 8192u;
    const bool big = ws_size >= need && ws_size >= (size_t)48u * 1024u * 1024u;
    char* base = big ? (char*)d_ws : (char*)out_oh;
    const size_t Z1o = big ? 1024u : 8u;
    const size_t E1o = Z1o + 33554432u;
    const size_t CMo = E1o + 524288u;
    const size_t ZNo = CMo + 4194304u;
    const size_t ENo = ZNo + 131072u;
    const size_t HIo = ENo + 4096u;

    unsigned short* Z1 = (unsigned short*)(base + Z1o);
    unsigned short* E1 = (unsigned short*)(base + E1o);
    unsigned long long* CM = (unsigned long long*)(base + CMo);
    float* ZN = (float*)(base + ZNo);
    float* EN = (float*)(base + ENo);
    int*   HI = big ? (int*)(base + HIo) : nullptr;
    float* SSE = (float*)d_ws;

    vq_prep<<<516, 256, 0, stream>>>(z, ew, Z1, E1, ZN, EN, SSE, HI);
    vq_argmin_mfma<<<2048, 256, 0, stream>>>(Z1, E1, EN, CM);
    vq_rescore<<<2048, 256, 0, stream>>>(z, ew, ZN, EN, CM, out_idx, out_zq, SSE,
                                         big ? out_oh : nullptr, HI);
    if (!big) vq_onehot<<<2048, 256, 0, stream>>>(out_idx, out_oh);
    vq_finalize<<<1, 1024, 0, stream>>>(HI, out_idx, SSE, out, out_ppl);
}